// Round 12
// baseline (576.422 us; speedup 1.0000x reference)
//
#include <hip/hip_runtime.h>
#include <hip/hip_bf16.h>

typedef __hip_bfloat16 bf16;
typedef __attribute__((ext_vector_type(8))) short short8;
typedef __attribute__((ext_vector_type(4))) float f32x4;
typedef __attribute__((ext_vector_type(4))) unsigned short ushort4_t;

#define TOK 100352      // B * H * W = 32*56*56
#define NWIN 2048       // B * 64 windows
#define CC 192
#define NHEAD 6
#define NT 49           // tokens per window

__device__ __forceinline__ float bf2f(bf16 v) { return __bfloat162float(v); }
__device__ __forceinline__ bf16 f2bf(float v) { return __float2bfloat16(v); }
__device__ __forceinline__ float b2f_bits(unsigned short u) {
    return __uint_as_float(((unsigned)u) << 16);
}

// dtype-agnostic input load: f=1 -> fp32, f=0 -> bf16
__device__ __forceinline__ float ldin(const void* p, size_t i, int f) {
    return f ? ((const float*)p)[i] : bf2f(((const bf16*)p)[i]);
}
// typed store/load for GEMM C/resid
__device__ __forceinline__ void stc(bf16* p, float v) { *p = f2bf(v); }
__device__ __forceinline__ void stc(float* p, float v) { *p = v; }
__device__ __forceinline__ float ldc(const bf16* p) { return bf2f(*p); }
__device__ __forceinline__ float ldc(const float* p) { return *p; }

// fast exact GELU: erf via Abramowitz-Stegun 7.1.26 (|eps| <= 1.5e-7, way below
// bf16 rounding). ~15 VALU inst vs ~50 for libm erff. (verified: absmax unchanged)
__device__ __forceinline__ float gelu_f(float v) {
    float z = v * 0.70710678118654752f;       // v / sqrt(2)
    float az = fabsf(z);
    float t = __builtin_amdgcn_rcpf(1.0f + 0.3275911f * az);
    float p = t * (0.254829592f + t * (-0.284496736f + t * (1.421413741f
            + t * (-1.453152027f + t * 1.061405429f))));
    float e = __expf(-az * az);
    float er = copysignf(1.0f - p * e, z);    // erf(z)
    return 0.5f * v * (1.0f + er);
}

// async global->LDS, 16B per lane; LDS dest is wave-uniform base + lane*16
__device__ __forceinline__ void gl_lds16(const bf16* g, bf16* l) {
    __builtin_amdgcn_global_load_lds(
        (const __attribute__((address_space(1))) unsigned int*)g,
        (__attribute__((address_space(3))) unsigned int*)l, 16, 0, 0);
}

// ---------------- input dtype probe ----------------
__global__ void dtype_probe_kernel(const void* xraw, int* flag) {
    const unsigned short* u = (const unsigned short*)xraw;
    int lane = threadIdx.x & 63;
    int weird = 0;
    for (int i = lane; i < 4096; i += 64) {
        unsigned int bits = ((unsigned int)u[2 * i]) << 16;
        float v = __uint_as_float(bits);
        if (!(fabsf(v) <= 1e10f)) weird++;
    }
    #pragma unroll
    for (int off = 32; off > 0; off >>= 1) weird += __shfl_xor(weird, off, 64);
    if (lane == 0) *flag = (weird > 256) ? 1 : 0;   // 1 = fp32 inputs, 0 = bf16 inputs
}

// ---------------- weight transpose + cast: out[n*K + k] = (bf16)in[k*N + n] ----------------
__global__ void transpose_kernel(const void* __restrict__ in, bf16* __restrict__ out,
                                 int K, int N, const int* __restrict__ flag) {
    int f = *flag;
    int idx = blockIdx.x * 256 + threadIdx.x;
    if (idx >= K * N) return;
    int nn = idx / K, kk = idx % K;
    out[idx] = f2bf(ldin(in, (size_t)kk * N + nn, f));
}

// ---------------- combined rel-bias + shift-mask table ----------------
// comb[wi][head][n][m] (64x6x64x64 bf16): rpb[ridx(n,m)][head] + mask[wi][n][m],
// padded to 64x64 with -1e30 on invalid key columns (m>=NT) so softmax zeroes them.
__global__ __launch_bounds__(256) void comb_kernel(
    const void* __restrict__ rpb, const void* __restrict__ mask,
    bf16* __restrict__ comb, const int* __restrict__ flag) {
    int f = *flag;
    int idx = blockIdx.x * 256 + threadIdx.x;   // 64*6*64*64 total
    int m = idx & 63;
    int n = (idx >> 6) & 63;
    int hw = idx >> 12;                          // wi*NHEAD + head
    int head = hw % NHEAD, wi = hw / NHEAD;
    float v;
    if (n < NT && m < NT) {
        int nr = n / 7, nc = n % 7, mr = m / 7, mc = m % 7;
        int ridx = (nr - mr + 6) * 13 + (nc - mc + 6);
        v = ldin(rpb, (size_t)ridx * NHEAD + head, f)
          + ldin(mask, (size_t)wi * NT * NT + n * NT + m, f);
    } else {
        v = -1e30f;
    }
    comb[idx] = f2bf(v);
}

// ---------------- LN1 + cyclic shift + window partition ----------------
__global__ __launch_bounds__(256) void ln1_window_kernel(
    const void* __restrict__ x, const void* __restrict__ g, const void* __restrict__ b,
    bf16* __restrict__ hwin, const int* __restrict__ flag) {
    int f = *flag;
    int wave = threadIdx.x >> 6, lane = threadIdx.x & 63;
    int t = blockIdx.x * 4 + wave;              // 0..TOK-1, window-layout index
    int bidx = t / (64 * NT);
    int r = t % (64 * NT);
    int wi = r / NT, n = r % NT;
    int wr = wi >> 3, wc = wi & 7;
    int nr = n / 7, nc = n % 7;
    int si = wr * 7 + nr, sj = wc * 7 + nc;     // shifted-image coords
    int oi = si + 3; if (oi >= 56) oi -= 56;    // source (original) coords
    int oj = sj + 3; if (oj >= 56) oj -= 56;
    size_t src = ((size_t)bidx * 3136 + oi * 56 + oj) * CC;
    float v0 = ldin(x, src + lane, f);
    float v1 = ldin(x, src + lane + 64, f);
    float v2 = ldin(x, src + lane + 128, f);
    float s = v0 + v1 + v2;
    float sq = v0 * v0 + v1 * v1 + v2 * v2;
    #pragma unroll
    for (int off = 32; off > 0; off >>= 1) {
        s  += __shfl_xor(s, off, 64);
        sq += __shfl_xor(sq, off, 64);
    }
    float mu = s * (1.f / 192.f);
    float var = fmaxf(sq * (1.f / 192.f) - mu * mu, 0.f);
    float rs = rsqrtf(var + 1e-5f);
    bf16* dst = hwin + (size_t)t * CC;
    dst[lane]       = f2bf((v0 - mu) * rs * ldin(g, lane, f)       + ldin(b, lane, f));
    dst[lane + 64]  = f2bf((v1 - mu) * rs * ldin(g, lane + 64, f)  + ldin(b, lane + 64, f));
    dst[lane + 128] = f2bf((v2 - mu) * rs * ldin(g, lane + 128, f) + ldin(b, lane + 128, f));
}

// ---------------- MFMA GEMM: C[M][Nc] = A[M][K] @ Wt[Nc][K]^T + bias ----
// BM=64, BN=64, BK=32, 128 threads (2 waves), each wave owns a 32x64 sub-tile
// (8 MFMA / K-step). 3-buffer depth-2 pipeline, counted s_waitcnt vmcnt(4)
// (4 gl_lds16/wave/step) + raw s_barrier; vmcnt(0) only at tail. 24 KB LDS ->
// 6 blocks/CU (12 waves) and 2x block count vs BM=128: more phase diversity so
// epilogue VALU overlaps other blocks' staging (fc1 is epilogue-VALU-heavy).
// Bank swizzle (round 11, conflicts 5.42M->0): linear gl_lds16 dest + pre-swizzled
// global SOURCE k-offset + matching swizzled read. XCD-aware bijective block swizzle.
// EPI: 0 = none, 1 = fast exact GELU, 2 = add residual (resid may alias C; same-elem RMW)
template <int EPI, typename CT>
__global__ __launch_bounds__(128, 3) void gemm_kernel(
    const bf16* __restrict__ A, const bf16* __restrict__ Wt,
    const void* __restrict__ bias, CT* __restrict__ C,
    const CT* __restrict__ resid, int M, int K, int Nc, const int* __restrict__ flag) {
    int f = *flag;
    __shared__ __align__(16) bf16 sb[3][4096];   // per buffer: A 64x32 @0, B 64x32 @2048
    int tid = threadIdx.x;
    int wave = tid >> 6, lane = tid & 63;        // wave in {0,1}
    int quad = lane >> 4, l16 = lane & 15;

    // XCD-aware swizzle (chunked, bijective when nwg % 8 == 0)
    int nwg = gridDim.x * gridDim.y;
    int bid = blockIdx.y * gridDim.x + blockIdx.x;
    int swz = bid;
    if ((nwg & 7) == 0) {
        int cpx = nwg >> 3;
        swz = (bid & 7) * cpx + (bid >> 3);
    }
    int bn = swz % gridDim.x, bm = swz / gridDim.x;

    // bank-conflict swizzle: source k-elem offset (staging) and read quad offset
    int swzk = (((lane & 3) ^ ((lane >> 3) & 3)) * 8);      // per-lane source k offset
    int q2   = (quad ^ ((l16 >> 1) & 3)) * 8;               // per-lane read k offset

    // per-lane global staging pointers (tile t = +t*32 along K), source pre-swizzled
    // A rows 0-63 in 4 chunks of 16; wave w stages chunks 2w, 2w+1. Same for B.
    const bf16* ag[2];
    const bf16* bg[2];
    #pragma unroll
    for (int j = 0; j < 2; j++) {
        int ch = wave * 2 + j;
        ag[j] = A  + (size_t)(bm * 64 + ch * 16 + (lane >> 2)) * K + swzk;
        bg[j] = Wt + (size_t)(bn * 64 + ch * 16 + (lane >> 2)) * K + swzk;
    }

    auto STAGE = [&](int t, int buf) {
        #pragma unroll
        for (int j = 0; j < 2; j++) {
            gl_lds16(ag[j] + (size_t)t * 32, &sb[buf][(wave * 2 + j) * 512]);
            gl_lds16(bg[j] + (size_t)t * 32, &sb[buf][2048 + (wave * 2 + j) * 512]);
        }
    };

    f32x4 acc[2][4];
    #pragma unroll
    for (int i = 0; i < 2; i++)
        #pragma unroll
        for (int j = 0; j < 4; j++)
            acc[i][j][0] = acc[i][j][1] = acc[i][j][2] = acc[i][j][3] = 0.f;

    const int nt = K >> 5;

    // prologue: tiles 0,1 in flight (8 loads/wave); wait tile 0 (4 newest in flight)
    STAGE(0, 0);
    STAGE(1, 1);
    asm volatile("s_waitcnt vmcnt(4)" ::: "memory");
    __builtin_amdgcn_s_barrier();

    int cur = 0;
    for (int t = 0; t < nt; t++) {
        if (t + 2 < nt) {
            int stg = cur + 2; if (stg >= 3) stg -= 3;
            STAGE(t + 2, stg);                  // overwrites buffer consumed at t-1
        }
        const bf16* sA = &sb[cur][0];
        const bf16* sB = &sb[cur][2048];
        short8 av[2], bv[4];
        #pragma unroll
        for (int tm = 0; tm < 2; tm++)
            av[tm] = *(const short8*)(&sA[(wave * 32 + tm * 16 + l16) * 32 + q2]);
        #pragma unroll
        for (int tn = 0; tn < 4; tn++)
            bv[tn] = *(const short8*)(&sB[(tn * 16 + l16) * 32 + q2]);
        #pragma unroll
        for (int tm = 0; tm < 2; tm++)
            #pragma unroll
            for (int tn = 0; tn < 4; tn++)
                acc[tm][tn] = __builtin_amdgcn_mfma_f32_16x16x32_bf16(av[tm], bv[tn], acc[tm][tn], 0, 0, 0);
        if (t + 1 < nt) {
            // tile t+1 resident (this wave's oldest 4 loads done); ds_reads done
            if (t + 2 < nt)
                asm volatile("s_waitcnt vmcnt(4) lgkmcnt(0)" ::: "memory");
            else
                asm volatile("s_waitcnt vmcnt(0) lgkmcnt(0)" ::: "memory");
            __builtin_amdgcn_s_barrier();
        }
        cur++; if (cur >= 3) cur -= 3;
    }

    #pragma unroll
    for (int tm = 0; tm < 2; tm++)
        #pragma unroll
        for (int tn = 0; tn < 4; tn++) {
            int col = bn * 64 + tn * 16 + l16;
            float bvs = ldin(bias, col, f);
            #pragma unroll
            for (int r = 0; r < 4; r++) {
                int row = bm * 64 + wave * 32 + tm * 16 + quad * 4 + r;
                float v = acc[tm][tn][r] + bvs;
                if (EPI == 1) v = gelu_f(v);
                if (EPI == 2) v += ldc(&resid[(size_t)row * Nc + col]);
                stc(&C[(size_t)row * Nc + col], v);
            }
        }
}

// ---------------- MFMA fused window attention: one block per (window, head) ----------------
// Swapped-operand QK^T (mfma(K,Q)) -> each lane holds 16 S-values of ONE query row.
// Softmax fully in-register. V staged with ONE uint4 load/thread (same row as Q/K,
// +384) then 8-way ds_write transpose scatter -> no scalar global loads. 6 blocks/CU.
__global__ __launch_bounds__(256) void attn_mfma_kernel(
    const bf16* __restrict__ qkv, const bf16* __restrict__ comb,
    bf16* __restrict__ attn_out, int wbase) {
    __shared__ __align__(16) bf16 Qs[64 * 40];
    __shared__ __align__(16) bf16 Ks[64 * 40];
    __shared__ __align__(16) bf16 Vt[32 * 72];
    __shared__ __align__(16) bf16 P[64 * 72];

    int head = blockIdx.x % NHEAD;
    int wl = blockIdx.x / NHEAD;      // window within chunk
    int wg = wbase + wl;              // global window
    int wi = wg & 63;                 // mask index (windows per image = 64)
    int t0 = wl * NT;                 // chunk-relative token base
    int tg = wg * NT;                 // global token base
    int tid = threadIdx.x;
    int wave = tid >> 6, lane = tid & 63;
    int quad = lane >> 4, l16 = lane & 15;

    // stage Q,K (64 rows x 32, zero rows >= 49); V via vector load + transpose scatter
    {
        int row = tid >> 2;
        int dc = (tid & 3) * 8;
        uint4 qv = make_uint4(0, 0, 0, 0), kv = qv, vv = qv;
        if (row < NT) {
            const bf16* base = qkv + (size_t)(t0 + row) * 576 + head * 32 + dc;
            qv = *(const uint4*)(base);
            kv = *(const uint4*)(base + 192);
            vv = *(const uint4*)(base + 384);
        }
        *(uint4*)(&Qs[row * 40 + dc]) = qv;
        *(uint4*)(&Ks[row * 40 + dc]) = kv;
        bf16 tv[8];
        *(uint4*)tv = vv;
        #pragma unroll
        for (int r = 0; r < 8; r++)
            Vt[(dc + r) * 72 + row] = tv[r];    // Vt[d][m], zeros for rows >= NT
    }
    __syncthreads();

    const float scale = 0.17677669529663687f;  // 1/sqrt(32)
    int tm = wave;
    int q = tm * 16 + l16;                      // this lane's query row
    const bf16* crow = comb + (((size_t)wi * NHEAD + head) * 64 + q) * 64;

    // S row in registers: s[tn][r] = S[q][tn*16 + quad*4 + r]
    float s[4][4];
    short8 bfrag = *(const short8*)(&Qs[q * 40 + quad * 8]);
    f32x4 z; z[0] = z[1] = z[2] = z[3] = 0.f;
    #pragma unroll
    for (int tn = 0; tn < 4; tn++) {
        short8 afrag = *(const short8*)(&Ks[(tn * 16 + l16) * 40 + quad * 8]);
        f32x4 acc = __builtin_amdgcn_mfma_f32_16x16x32_bf16(afrag, bfrag, z, 0, 0, 0);
        ushort4_t cb = *(const ushort4_t*)(crow + tn * 16 + quad * 4);
        s[tn][0] = acc[0] * scale + b2f_bits(cb[0]);
        s[tn][1] = acc[1] * scale + b2f_bits(cb[1]);
        s[tn][2] = acc[2] * scale + b2f_bits(cb[2]);
        s[tn][3] = acc[3] * scale + b2f_bits(cb[3]);
    }

    // in-register softmax over the 64 keys of query q (16 in-lane + quad group)
    float mx = s[0][0];
    #pragma unroll
    for (int tn = 0; tn < 4; tn++)
        #pragma unroll
        for (int r = 0; r < 4; r++) mx = fmaxf(mx, s[tn][r]);
    mx = fmaxf(mx, __shfl_xor(mx, 16, 64));
    mx = fmaxf(mx, __shfl_xor(mx, 32, 64));
    float sm = 0.f;
    #pragma unroll
    for (int tn = 0; tn < 4; tn++)
        #pragma unroll
        for (int r = 0; r < 4; r++) { s[tn][r] = __expf(s[tn][r] - mx); sm += s[tn][r]; }
    sm += __shfl_xor(sm, 16, 64);
    sm += __shfl_xor(sm, 32, 64);
    float inv = 1.0f / sm;

    // write P row segments (4 bf16 = 8B per store); each wave touches only its own rows
    #pragma unroll
    for (int tn = 0; tn < 4; tn++) {
        bf16 pk[4];
        #pragma unroll
        for (int r = 0; r < 4; r++) pk[r] = f2bf(s[tn][r] * inv);
        *(uint2*)(&P[q * 72 + tn * 16 + quad * 4]) = *(const uint2*)pk;
    }
    __syncthreads();

    // O = P @ V   (M=64 rows, N=32 dims, K=64 over keys)
    f32x4 oacc[2];
    oacc[0][0] = oacc[0][1] = oacc[0][2] = oacc[0][3] = 0.f;
    oacc[1] = oacc[0];
    #pragma unroll
    for (int kc = 0; kc < 2; kc++) {
        short8 pa = *(const short8*)(&P[(tm * 16 + l16) * 72 + kc * 32 + quad * 8]);
        #pragma unroll
        for (int tn = 0; tn < 2; tn++) {
            short8 vb = *(const short8*)(&Vt[(tn * 16 + l16) * 72 + kc * 32 + quad * 8]);
            oacc[tn] = __builtin_amdgcn_mfma_f32_16x16x32_bf16(pa, vb, oacc[tn], 0, 0, 0);
        }
    }
    #pragma unroll
    for (int tn = 0; tn < 2; tn++) {
        #pragma unroll
        for (int r = 0; r < 4; r++) {
            int n = tm * 16 + quad * 4 + r;
            int d = tn * 16 + l16;
            if (n < NT)
                attn_out[(size_t)(tg + n) * CC + head * 32 + d] = f2bf(oacc[tn][r]);
        }
    }
}

// ---------------- window-reverse + unshift + residual + LN2 ----------------
// x1 (FP32) goes into d_out (read back by FC2 epilogue, overwritten in place)
__global__ __launch_bounds__(256) void resid_ln2_kernel(
    const void* __restrict__ x, const bf16* __restrict__ proj,
    const void* __restrict__ g, const void* __restrict__ b,
    float* __restrict__ x1, bf16* __restrict__ h2, const int* __restrict__ flag) {
    int f = *flag;
    int wave = threadIdx.x >> 6, lane = threadIdx.x & 63;
    int tok = blockIdx.x * 4 + wave;          // original token order
    int bidx = tok / 3136;
    int r = tok % 3136;
    int i = r / 56, j = r % 56;
    int si = i + 53; if (si >= 56) si -= 56;  // (i - 3) mod 56
    int sj = j + 53; if (sj >= 56) sj -= 56;
    int wi = (si / 7) * 8 + sj / 7;
    int n = (si % 7) * 7 + (sj % 7);
    size_t tw = ((size_t)bidx * 64 + wi) * NT + n;
    const bf16* ps = proj + tw * CC;
    size_t xs = (size_t)tok * CC;
    float v0 = ldin(x, xs + lane, f)       + bf2f(ps[lane]);
    float v1 = ldin(x, xs + lane + 64, f)  + bf2f(ps[lane + 64]);
    float v2 = ldin(x, xs + lane + 128, f) + bf2f(ps[lane + 128]);
    float* xd = x1 + (size_t)tok * CC;
    xd[lane] = v0; xd[lane + 64] = v1; xd[lane + 128] = v2;
    float s = v0 + v1 + v2;
    float sq = v0 * v0 + v1 * v1 + v2 * v2;
    #pragma unroll
    for (int off = 32; off > 0; off >>= 1) {
        s  += __shfl_xor(s, off, 64);
        sq += __shfl_xor(sq, off, 64);
    }
    float mu = s * (1.f / 192.f);
    float var = fmaxf(sq * (1.f / 192.f) - mu * mu, 0.f);
    float rs = rsqrtf(var + 1e-5f);
    bf16* dst = h2 + (size_t)tok * CC;
    dst[lane]       = f2bf((v0 - mu) * rs * ldin(g, lane, f)       + ldin(b, lane, f));
    dst[lane + 64]  = f2bf((v1 - mu) * rs * ldin(g, lane + 64, f)  + ldin(b, lane + 64, f));
    dst[lane + 128] = f2bf((v2 - mu) * rs * ldin(g, lane + 128, f) + ldin(b, lane + 128, f));
}

extern "C" void kernel_launch(void* const* d_in, const int* in_sizes, int n_in,
                              void* d_out, int out_size, void* d_ws, size_t ws_size,
                              hipStream_t stream) {
    const void* x        = d_in[0];
    const void* attnmask = d_in[1];
    const void* ln1_g    = d_in[2];
    const void* ln1_b    = d_in[3];
    const void* qkv_w    = d_in[4];
    const void* qkv_b    = d_in[5];
    const void* rpb      = d_in[6];
    const void* proj_w   = d_in[7];
    const void* proj_b   = d_in[8];
    const void* ln2_g    = d_in[9];
    const void* ln2_b    = d_in[10];
    const void* fc1_w    = d_in[11];
    const void* fc1_b    = d_in[12];
    const void* fc2_w    = d_in[13];
    const void* fc2_b    = d_in[14];
    float* out = (float*)d_out;          // output fp32 (reference dtype)
    char* ws = (char*)d_ws;

    const size_t RSZ = (size_t)TOK * CC * sizeof(bf16);   // 38,535,168
    const size_t WEXT = 442368 * sizeof(bf16)             // 4 transposed weights
                      + (size_t)64 * NHEAD * 64 * 64 * sizeof(bf16)  // comb
                      + 64;                                // flag + pad
    const size_t NEED_BIG = 5 * RSZ + WEXT;                // ~196.7 MB

    const int M = TOK;

    if (ws_size >= NEED_BIG) {
        // ---------------- unchunked path (uses ~197 MB of workspace) ----------------
        // [0,RSZ):      h_win [ln1->qkv]  -> projbuf [proj->resid] -> m1 head
        // [RSZ,4RSZ):   qkv (3*RSZ) [qkv->attn] -> m1 tail (m1 = [0,4RSZ))
        // [4RSZ,5RSZ):  attn_out [attn->proj] -> h2 [resid->fc1]
        // [5RSZ,...):   transposed weights + comb + flag
        bf16* h_win    = (bf16*)(ws);
        bf16* qkvbuf   = (bf16*)(ws + RSZ);
        bf16* attn_out = (bf16*)(ws + 4 * RSZ);
        bf16* projbuf  = (bf16*)(ws);
        bf16* h2       = (bf16*)(ws + 4 * RSZ);
        bf16* m1buf    = (bf16*)(ws);
        bf16* qkvT     = (bf16*)(ws + 5 * RSZ);
        bf16* projT    = qkvT + 192 * 576;
        bf16* fc1T     = projT + 192 * 192;
        bf16* fc2T     = fc1T + 192 * 768;
        bf16* combT    = fc2T + 768 * 192;
        int*  flag     = (int*)(combT + 64 * NHEAD * 64 * 64);

        dtype_probe_kernel<<<1, 64, 0, stream>>>(x, flag);
        transpose_kernel<<<(192 * 576 + 255) / 256, 256, 0, stream>>>(qkv_w, qkvT, 192, 576, flag);
        transpose_kernel<<<(192 * 192 + 255) / 256, 256, 0, stream>>>(proj_w, projT, 192, 192, flag);
        transpose_kernel<<<(192 * 768 + 255) / 256, 256, 0, stream>>>(fc1_w, fc1T, 192, 768, flag);
        transpose_kernel<<<(768 * 192 + 255) / 256, 256, 0, stream>>>(fc2_w, fc2T, 768, 192, flag);
        comb_kernel<<<(64 * NHEAD * 64 * 64) / 256, 256, 0, stream>>>(rpb, attnmask, combT, flag);

        ln1_window_kernel<<<TOK / 4, 256, 0, stream>>>(x, ln1_g, ln1_b, h_win, flag);

        gemm_kernel<0, bf16><<<dim3(576 / 64, M / 64), 128, 0, stream>>>(
            h_win, qkvT, qkv_b, qkvbuf, (const bf16*)nullptr, M, 192, 576, flag);
        attn_mfma_kernel<<<NWIN * NHEAD, 256, 0, stream>>>(qkvbuf, combT, attn_out, 0);

        gemm_kernel<0, bf16><<<dim3(192 / 64, M / 64), 128, 0, stream>>>(
            attn_out, projT, proj_b, projbuf, (const bf16*)nullptr, M, 192, 192, flag);

        resid_ln2_kernel<<<TOK / 4, 256, 0, stream>>>(x, projbuf, ln2_g, ln2_b, out, h2, flag);

        gemm_kernel<1, bf16><<<dim3(768 / 64, M / 64), 128, 0, stream>>>(
            h2, fc1T, fc1_b, m1buf, (const bf16*)nullptr, M, 192, 768, flag);
        gemm_kernel<2, float><<<dim3(192 / 64, M / 64), 128, 0, stream>>>(
            m1buf, fc2T, fc2_b, out, (const float*)out, M, 768, 192, flag);
    } else {
        // ---------------- chunked fallback (~119.6 MB peak, time-disjoint reuse) ----------------
        bf16* h_win    = (bf16*)(ws);
        bf16* m1buf    = (bf16*)(ws);
        bf16* attn_out = (bf16*)(ws + RSZ);
        bf16* h2       = (bf16*)(ws + RSZ);
        bf16* qkvchunk = (bf16*)(ws + 2 * RSZ);
        bf16* projbuf  = (bf16*)(ws + 2 * RSZ);
        bf16* combT    = (bf16*)(ws + 2 * RSZ + 28901376);    // after qkv chunk, within R2
        bf16* qkvT     = (bf16*)(ws + 3 * RSZ);
        bf16* projT    = qkvT + 192 * 576;
        bf16* fc1T     = projT + 192 * 192;
        bf16* fc2T     = fc1T + 192 * 768;
        int*  flag     = (int*)(fc2T + 768 * 192);

        dtype_probe_kernel<<<1, 64, 0, stream>>>(x, flag);
        transpose_kernel<<<(192 * 576 + 255) / 256, 256, 0, stream>>>(qkv_w, qkvT, 192, 576, flag);
        transpose_kernel<<<(192 * 192 + 255) / 256, 256, 0, stream>>>(proj_w, projT, 192, 192, flag);
        transpose_kernel<<<(192 * 768 + 255) / 256, 256, 0, stream>>>(fc1_w, fc1T, 192, 768, flag);
        transpose_kernel<<<(768 * 192 + 255) / 256, 256, 0, stream>>>(fc2_w, fc2T, 768, 192, flag);
        comb_kernel<<<(64 * NHEAD * 64 * 64) / 256, 256, 0, stream>>>(rpb, attnmask, combT, flag);

        ln1_window_kernel<<<TOK / 4, 256, 0, stream>>>(x, ln1_g, ln1_b, h_win, flag);

        const int QCH = 4, QW = NWIN / QCH;          // 512 windows/chunk
        const int QROWS = QW * NT;                   // 25088 rows (divisible by 64)
        for (int c = 0; c < QCH; c++) {
            const bf16* a = h_win + (size_t)c * QROWS * CC;
            gemm_kernel<0, bf16><<<dim3(576 / 64, QROWS / 64), 128, 0, stream>>>(
                a, qkvT, qkv_b, qkvchunk, (const bf16*)nullptr, QROWS, 192, 576, flag);
            attn_mfma_kernel<<<QW * NHEAD, 256, 0, stream>>>(
                qkvchunk, combT, attn_out, c * QW);
        }

        gemm_kernel<0, bf16><<<dim3(192 / 64, M / 64), 128, 0, stream>>>(
            attn_out, projT, proj_b, projbuf, (const bf16*)nullptr, M, 192, 192, flag);

        resid_ln2_kernel<<<TOK / 4, 256, 0, stream>>>(x, projbuf, ln2_g, ln2_b, out, h2, flag);

        const int MCH = 4, MR = TOK / MCH;           // 25088 rows/chunk (divisible by 64)
        for (int c = 0; c < MCH; c++) {
            const bf16* a = h2 + (size_t)c * MR * CC;
            float* oc = out + (size_t)c * MR * CC;
            gemm_kernel<1, bf16><<<dim3(768 / 64, MR / 64), 128, 0, stream>>>(
                a, fc1T, fc1_b, m1buf, (const bf16*)nullptr, MR, 192, 768, flag);
            gemm_kernel<2, float><<<dim3(192 / 64, MR / 64), 128, 0, stream>>>(
                m1buf, fc2T, fc2_b, oc, (const float*)oc, MR, 768, 192, flag);
        }
    }
}

// Round 13
// 527.664 us; speedup vs baseline: 1.0924x; 1.0924x over previous
//
#include <hip/hip_runtime.h>
#include <hip/hip_bf16.h>

typedef __hip_bfloat16 bf16;
typedef __attribute__((ext_vector_type(8))) short short8;
typedef __attribute__((ext_vector_type(4))) float f32x4;
typedef __attribute__((ext_vector_type(4))) unsigned short ushort4_t;

#define TOK 100352      // B * H * W = 32*56*56
#define NWIN 2048       // B * 64 windows
#define CC 192
#define NHEAD 6
#define NT 49           // tokens per window

__device__ __forceinline__ float bf2f(bf16 v) { return __bfloat162float(v); }
__device__ __forceinline__ bf16 f2bf(float v) { return __float2bfloat16(v); }
__device__ __forceinline__ float b2f_bits(unsigned short u) {
    return __uint_as_float(((unsigned)u) << 16);
}

// dtype-agnostic input load: f=1 -> fp32, f=0 -> bf16
__device__ __forceinline__ float ldin(const void* p, size_t i, int f) {
    return f ? ((const float*)p)[i] : bf2f(((const bf16*)p)[i]);
}
// typed store/load for GEMM C/resid
__device__ __forceinline__ void stc(bf16* p, float v) { *p = f2bf(v); }
__device__ __forceinline__ void stc(float* p, float v) { *p = v; }
__device__ __forceinline__ float ldc(const bf16* p) { return bf2f(*p); }
__device__ __forceinline__ float ldc(const float* p) { return *p; }

// fast exact GELU: erf via Abramowitz-Stegun 7.1.26 (|eps| <= 1.5e-7, way below
// bf16 rounding). ~15 VALU inst vs ~50 for libm erff. (verified: absmax unchanged)
__device__ __forceinline__ float gelu_f(float v) {
    float z = v * 0.70710678118654752f;       // v / sqrt(2)
    float az = fabsf(z);
    float t = __builtin_amdgcn_rcpf(1.0f + 0.3275911f * az);
    float p = t * (0.254829592f + t * (-0.284496736f + t * (1.421413741f
            + t * (-1.453152027f + t * 1.061405429f))));
    float e = __expf(-az * az);
    float er = copysignf(1.0f - p * e, z);    // erf(z)
    return 0.5f * v * (1.0f + er);
}

// async global->LDS, 16B per lane; LDS dest is wave-uniform base + lane*16
__device__ __forceinline__ void gl_lds16(const bf16* g, bf16* l) {
    __builtin_amdgcn_global_load_lds(
        (const __attribute__((address_space(1))) unsigned int*)g,
        (__attribute__((address_space(3))) unsigned int*)l, 16, 0, 0);
}

// ---------------- input dtype probe ----------------
__global__ void dtype_probe_kernel(const void* xraw, int* flag) {
    const unsigned short* u = (const unsigned short*)xraw;
    int lane = threadIdx.x & 63;
    int weird = 0;
    for (int i = lane; i < 4096; i += 64) {
        unsigned int bits = ((unsigned int)u[2 * i]) << 16;
        float v = __uint_as_float(bits);
        if (!(fabsf(v) <= 1e10f)) weird++;
    }
    #pragma unroll
    for (int off = 32; off > 0; off >>= 1) weird += __shfl_xor(weird, off, 64);
    if (lane == 0) *flag = (weird > 256) ? 1 : 0;   // 1 = fp32 inputs, 0 = bf16 inputs
}

// ---------------- weight transpose + cast: out[n*K + k] = (bf16)in[k*N + n] ----------------
__global__ void transpose_kernel(const void* __restrict__ in, bf16* __restrict__ out,
                                 int K, int N, const int* __restrict__ flag) {
    int f = *flag;
    int idx = blockIdx.x * 256 + threadIdx.x;
    if (idx >= K * N) return;
    int nn = idx / K, kk = idx % K;
    out[idx] = f2bf(ldin(in, (size_t)kk * N + nn, f));
}

// ---------------- combined rel-bias + shift-mask table ----------------
// comb[wi][head][n][m] (64x6x64x64 bf16): rpb[ridx(n,m)][head] + mask[wi][n][m],
// padded to 64x64 with -1e30 on invalid key columns (m>=NT) so softmax zeroes them.
__global__ __launch_bounds__(256) void comb_kernel(
    const void* __restrict__ rpb, const void* __restrict__ mask,
    bf16* __restrict__ comb, const int* __restrict__ flag) {
    int f = *flag;
    int idx = blockIdx.x * 256 + threadIdx.x;   // 64*6*64*64 total
    int m = idx & 63;
    int n = (idx >> 6) & 63;
    int hw = idx >> 12;                          // wi*NHEAD + head
    int head = hw % NHEAD, wi = hw / NHEAD;
    float v;
    if (n < NT && m < NT) {
        int nr = n / 7, nc = n % 7, mr = m / 7, mc = m % 7;
        int ridx = (nr - mr + 6) * 13 + (nc - mc + 6);
        v = ldin(rpb, (size_t)ridx * NHEAD + head, f)
          + ldin(mask, (size_t)wi * NT * NT + n * NT + m, f);
    } else {
        v = -1e30f;
    }
    comb[idx] = f2bf(v);
}

// ---------------- LN1 + cyclic shift + window partition ----------------
__global__ __launch_bounds__(256) void ln1_window_kernel(
    const void* __restrict__ x, const void* __restrict__ g, const void* __restrict__ b,
    bf16* __restrict__ hwin, const int* __restrict__ flag) {
    int f = *flag;
    int wave = threadIdx.x >> 6, lane = threadIdx.x & 63;
    int t = blockIdx.x * 4 + wave;              // 0..TOK-1, window-layout index
    int bidx = t / (64 * NT);
    int r = t % (64 * NT);
    int wi = r / NT, n = r % NT;
    int wr = wi >> 3, wc = wi & 7;
    int nr = n / 7, nc = n % 7;
    int si = wr * 7 + nr, sj = wc * 7 + nc;     // shifted-image coords
    int oi = si + 3; if (oi >= 56) oi -= 56;    // source (original) coords
    int oj = sj + 3; if (oj >= 56) oj -= 56;
    size_t src = ((size_t)bidx * 3136 + oi * 56 + oj) * CC;
    float v0 = ldin(x, src + lane, f);
    float v1 = ldin(x, src + lane + 64, f);
    float v2 = ldin(x, src + lane + 128, f);
    float s = v0 + v1 + v2;
    float sq = v0 * v0 + v1 * v1 + v2 * v2;
    #pragma unroll
    for (int off = 32; off > 0; off >>= 1) {
        s  += __shfl_xor(s, off, 64);
        sq += __shfl_xor(sq, off, 64);
    }
    float mu = s * (1.f / 192.f);
    float var = fmaxf(sq * (1.f / 192.f) - mu * mu, 0.f);
    float rs = rsqrtf(var + 1e-5f);
    bf16* dst = hwin + (size_t)t * CC;
    dst[lane]       = f2bf((v0 - mu) * rs * ldin(g, lane, f)       + ldin(b, lane, f));
    dst[lane + 64]  = f2bf((v1 - mu) * rs * ldin(g, lane + 64, f)  + ldin(b, lane + 64, f));
    dst[lane + 128] = f2bf((v2 - mu) * rs * ldin(g, lane + 128, f) + ldin(b, lane + 128, f));
}

// ---------------- MFMA GEMM: C[M][Nc] = A[M][K] @ Wt[Nc][K]^T + bias ----
// BM=128, BN=64, BK=32. 4 waves, each owns a 32x64 output sub-tile (8 MFMA / K-step).
// 3-buffer depth-2 pipeline: stage tile t+2 each iter, counted s_waitcnt vmcnt(3)
// + raw s_barrier (never drain to 0 in the loop) -> load latency spans 2 iterations.
// Bank swizzle (round 11, conflicts 5.42M->0): linear gl_lds16 dest + pre-swizzled
// global SOURCE k-offset + matching swizzled read. XCD-aware bijective block swizzle.
// EPI: 0 = none, 1 = fast exact GELU, 2 = add residual (resid may alias C; same-elem RMW)
template <int EPI, typename CT>
__global__ __launch_bounds__(256, 4) void gemm_kernel(
    const bf16* __restrict__ A, const bf16* __restrict__ Wt,
    const void* __restrict__ bias, CT* __restrict__ C,
    const CT* __restrict__ resid, int M, int K, int Nc, const int* __restrict__ flag) {
    int f = *flag;
    __shared__ __align__(16) bf16 sb[3][6144];   // per buffer: A 128x32 @0, B 64x32 @4096
    int tid = threadIdx.x;
    int wave = tid >> 6, lane = tid & 63;
    int quad = lane >> 4, l16 = lane & 15;

    // XCD-aware swizzle (chunked, bijective when nwg % 8 == 0)
    int nwg = gridDim.x * gridDim.y;
    int bid = blockIdx.y * gridDim.x + blockIdx.x;
    int swz = bid;
    if ((nwg & 7) == 0) {
        int cpx = nwg >> 3;
        swz = (bid & 7) * cpx + (bid >> 3);
    }
    int bn = swz % gridDim.x, bm = swz / gridDim.x;

    // bank-conflict swizzle: source k-elem offset (staging) and read quad offset
    int swzk = (((lane & 3) ^ ((lane >> 3) & 3)) * 8);      // per-lane source k offset
    int q2   = (quad ^ ((l16 >> 1) & 3)) * 8;               // per-lane read k offset

    // per-lane global staging pointers (tile t = +t*32 along K), source pre-swizzled
    const bf16* ag[2];
    #pragma unroll
    for (int j = 0; j < 2; j++)
        ag[j] = A + (size_t)(bm * 128 + (wave * 2 + j) * 16 + (lane >> 2)) * K + swzk;
    const bf16* bg = Wt + (size_t)(bn * 64 + wave * 16 + (lane >> 2)) * K + swzk;

    auto STAGE = [&](int t, int buf) {
        gl_lds16(ag[0] + (size_t)t * 32, &sb[buf][(wave * 2 + 0) * 512]);
        gl_lds16(ag[1] + (size_t)t * 32, &sb[buf][(wave * 2 + 1) * 512]);
        gl_lds16(bg    + (size_t)t * 32, &sb[buf][4096 + wave * 512]);
    };

    f32x4 acc[2][4];
    #pragma unroll
    for (int i = 0; i < 2; i++)
        #pragma unroll
        for (int j = 0; j < 4; j++)
            acc[i][j][0] = acc[i][j][1] = acc[i][j][2] = acc[i][j][3] = 0.f;

    const int nt = K >> 5;

    // prologue: tiles 0,1 in flight; wait tile 0 only (3 of 6 loads)
    STAGE(0, 0);
    STAGE(1, 1);
    asm volatile("s_waitcnt vmcnt(3)" ::: "memory");
    __builtin_amdgcn_s_barrier();

    int cur = 0;
    for (int t = 0; t < nt; t++) {
        if (t + 2 < nt) {
            int stg = cur + 2; if (stg >= 3) stg -= 3;
            STAGE(t + 2, stg);                  // overwrites buffer consumed at t-1
        }
        const bf16* sA = &sb[cur][0];
        const bf16* sB = &sb[cur][4096];
        short8 av[2], bv[4];
        #pragma unroll
        for (int tm = 0; tm < 2; tm++)
            av[tm] = *(const short8*)(&sA[(wave * 32 + tm * 16 + l16) * 32 + q2]);
        #pragma unroll
        for (int tn = 0; tn < 4; tn++)
            bv[tn] = *(const short8*)(&sB[(tn * 16 + l16) * 32 + q2]);
        #pragma unroll
        for (int tm = 0; tm < 2; tm++)
            #pragma unroll
            for (int tn = 0; tn < 4; tn++)
                acc[tm][tn] = __builtin_amdgcn_mfma_f32_16x16x32_bf16(av[tm], bv[tn], acc[tm][tn], 0, 0, 0);
        if (t + 1 < nt) {
            // tile t+1 resident (oldest 3 loads done); this wave's ds_reads done
            if (t + 2 < nt)
                asm volatile("s_waitcnt vmcnt(3) lgkmcnt(0)" ::: "memory");
            else
                asm volatile("s_waitcnt vmcnt(0) lgkmcnt(0)" ::: "memory");
            __builtin_amdgcn_s_barrier();
        }
        cur++; if (cur >= 3) cur -= 3;
    }

    #pragma unroll
    for (int tm = 0; tm < 2; tm++)
        #pragma unroll
        for (int tn = 0; tn < 4; tn++) {
            int col = bn * 64 + tn * 16 + l16;
            float bvs = ldin(bias, col, f);
            #pragma unroll
            for (int r = 0; r < 4; r++) {
                int row = bm * 128 + wave * 32 + tm * 16 + quad * 4 + r;
                float v = acc[tm][tn][r] + bvs;
                if (EPI == 1) v = gelu_f(v);
                if (EPI == 2) v += ldc(&resid[(size_t)row * Nc + col]);
                stc(&C[(size_t)row * Nc + col], v);
            }
        }
}

// ---------------- MFMA fused window attention: one block per (window, head) ----------------
// Swapped-operand QK^T (mfma(K,Q)) -> each lane holds 16 S-values of ONE query row.
// Softmax fully in-register. V staged with ONE uint4 load/thread + ds transpose scatter.
// P is WAVE-LOCAL (wave tm writes and reads only rows tm*16..tm*16+15) -> no barrier
// between softmax and PV (same-wave LDS ordering via lgkmcnt). comb loads hoisted
// ahead of the QK^T MFMAs so their global latency overlaps compute. 6 blocks/CU.
__global__ __launch_bounds__(256) void attn_mfma_kernel(
    const bf16* __restrict__ qkv, const bf16* __restrict__ comb,
    bf16* __restrict__ attn_out, int wbase) {
    __shared__ __align__(16) bf16 Qs[64 * 40];
    __shared__ __align__(16) bf16 Ks[64 * 40];
    __shared__ __align__(16) bf16 Vt[32 * 72];
    __shared__ __align__(16) bf16 P[64 * 72];

    int head = blockIdx.x % NHEAD;
    int wl = blockIdx.x / NHEAD;      // window within chunk
    int wg = wbase + wl;              // global window
    int wi = wg & 63;                 // mask index (windows per image = 64)
    int t0 = wl * NT;                 // chunk-relative token base
    int tg = wg * NT;                 // global token base
    int tid = threadIdx.x;
    int wave = tid >> 6, lane = tid & 63;
    int quad = lane >> 4, l16 = lane & 15;

    // stage Q,K (64 rows x 32, zero rows >= 49); V via vector load + transpose scatter
    {
        int row = tid >> 2;
        int dc = (tid & 3) * 8;
        uint4 qv = make_uint4(0, 0, 0, 0), kv = qv, vv = qv;
        if (row < NT) {
            const bf16* base = qkv + (size_t)(t0 + row) * 576 + head * 32 + dc;
            qv = *(const uint4*)(base);
            kv = *(const uint4*)(base + 192);
            vv = *(const uint4*)(base + 384);
        }
        *(uint4*)(&Qs[row * 40 + dc]) = qv;
        *(uint4*)(&Ks[row * 40 + dc]) = kv;
        bf16 tv[8];
        *(uint4*)tv = vv;
        #pragma unroll
        for (int r = 0; r < 8; r++)
            Vt[(dc + r) * 72 + row] = tv[r];    // Vt[d][m], zeros for rows >= NT
    }
    __syncthreads();

    const float scale = 0.17677669529663687f;  // 1/sqrt(32)
    int tm = wave;
    int q = tm * 16 + l16;                      // this lane's query row
    const bf16* crow = comb + (((size_t)wi * NHEAD + head) * 64 + q) * 64;

    // hoist comb loads: global latency overlaps the QK^T MFMAs below
    ushort4_t cb[4];
    #pragma unroll
    for (int tn = 0; tn < 4; tn++)
        cb[tn] = *(const ushort4_t*)(crow + tn * 16 + quad * 4);

    // S row in registers: s[tn][r] = S[q][tn*16 + quad*4 + r]
    float s[4][4];
    short8 bfrag = *(const short8*)(&Qs[q * 40 + quad * 8]);
    f32x4 z; z[0] = z[1] = z[2] = z[3] = 0.f;
    #pragma unroll
    for (int tn = 0; tn < 4; tn++) {
        short8 afrag = *(const short8*)(&Ks[(tn * 16 + l16) * 40 + quad * 8]);
        f32x4 acc = __builtin_amdgcn_mfma_f32_16x16x32_bf16(afrag, bfrag, z, 0, 0, 0);
        s[tn][0] = acc[0] * scale + b2f_bits(cb[tn][0]);
        s[tn][1] = acc[1] * scale + b2f_bits(cb[tn][1]);
        s[tn][2] = acc[2] * scale + b2f_bits(cb[tn][2]);
        s[tn][3] = acc[3] * scale + b2f_bits(cb[tn][3]);
    }

    // in-register softmax over the 64 keys of query q (16 in-lane + quad group)
    float mx = s[0][0];
    #pragma unroll
    for (int tn = 0; tn < 4; tn++)
        #pragma unroll
        for (int r = 0; r < 4; r++) mx = fmaxf(mx, s[tn][r]);
    mx = fmaxf(mx, __shfl_xor(mx, 16, 64));
    mx = fmaxf(mx, __shfl_xor(mx, 32, 64));
    float sm = 0.f;
    #pragma unroll
    for (int tn = 0; tn < 4; tn++)
        #pragma unroll
        for (int r = 0; r < 4; r++) { s[tn][r] = __expf(s[tn][r] - mx); sm += s[tn][r]; }
    sm += __shfl_xor(sm, 16, 64);
    sm += __shfl_xor(sm, 32, 64);
    float inv = 1.0f / sm;

    // write P row segments; wave tm touches ONLY rows tm*16..tm*16+15
    #pragma unroll
    for (int tn = 0; tn < 4; tn++) {
        bf16 pk[4];
        #pragma unroll
        for (int r = 0; r < 4; r++) pk[r] = f2bf(s[tn][r] * inv);
        *(uint2*)(&P[q * 72 + tn * 16 + quad * 4]) = *(const uint2*)pk;
    }
    // no barrier: PV below reads only this wave's P rows (same-wave LDS ordering)

    // O = P @ V   (M=64 rows, N=32 dims, K=64 over keys)
    f32x4 oacc[2];
    oacc[0][0] = oacc[0][1] = oacc[0][2] = oacc[0][3] = 0.f;
    oacc[1] = oacc[0];
    #pragma unroll
    for (int kc = 0; kc < 2; kc++) {
        short8 pa = *(const short8*)(&P[(tm * 16 + l16) * 72 + kc * 32 + quad * 8]);
        #pragma unroll
        for (int tn = 0; tn < 2; tn++) {
            short8 vb = *(const short8*)(&Vt[(tn * 16 + l16) * 72 + kc * 32 + quad * 8]);
            oacc[tn] = __builtin_amdgcn_mfma_f32_16x16x32_bf16(pa, vb, oacc[tn], 0, 0, 0);
        }
    }
    #pragma unroll
    for (int tn = 0; tn < 2; tn++) {
        #pragma unroll
        for (int r = 0; r < 4; r++) {
            int n = tm * 16 + quad * 4 + r;
            int d = tn * 16 + l16;
            if (n < NT)
                attn_out[(size_t)(tg + n) * CC + head * 32 + d] = f2bf(oacc[tn][r]);
        }
    }
}

// ---------------- window-reverse + unshift + residual + LN2 ----------------
// x1 (FP32) goes into d_out (read back by FC2 epilogue, overwritten in place)
__global__ __launch_bounds__(256) void resid_ln2_kernel(
    const void* __restrict__ x, const bf16* __restrict__ proj,
    const void* __restrict__ g, const void* __restrict__ b,
    float* __restrict__ x1, bf16* __restrict__ h2, const int* __restrict__ flag) {
    int f = *flag;
    int wave = threadIdx.x >> 6, lane = threadIdx.x & 63;
    int tok = blockIdx.x * 4 + wave;          // original token order
    int bidx = tok / 3136;
    int r = tok % 3136;
    int i = r / 56, j = r % 56;
    int si = i + 53; if (si >= 56) si -= 56;  // (i - 3) mod 56
    int sj = j + 53; if (sj >= 56) sj -= 56;
    int wi = (si / 7) * 8 + sj / 7;
    int n = (si % 7) * 7 + (sj % 7);
    size_t tw = ((size_t)bidx * 64 + wi) * NT + n;
    const bf16* ps = proj + tw * CC;
    size_t xs = (size_t)tok * CC;
    float v0 = ldin(x, xs + lane, f)       + bf2f(ps[lane]);
    float v1 = ldin(x, xs + lane + 64, f)  + bf2f(ps[lane + 64]);
    float v2 = ldin(x, xs + lane + 128, f) + bf2f(ps[lane + 128]);
    float* xd = x1 + (size_t)tok * CC;
    xd[lane] = v0; xd[lane + 64] = v1; xd[lane + 128] = v2;
    float s = v0 + v1 + v2;
    float sq = v0 * v0 + v1 * v1 + v2 * v2;
    #pragma unroll
    for (int off = 32; off > 0; off >>= 1) {
        s  += __shfl_xor(s, off, 64);
        sq += __shfl_xor(sq, off, 64);
    }
    float mu = s * (1.f / 192.f);
    float var = fmaxf(sq * (1.f / 192.f) - mu * mu, 0.f);
    float rs = rsqrtf(var + 1e-5f);
    bf16* dst = h2 + (size_t)tok * CC;
    dst[lane]       = f2bf((v0 - mu) * rs * ldin(g, lane, f)       + ldin(b, lane, f));
    dst[lane + 64]  = f2bf((v1 - mu) * rs * ldin(g, lane + 64, f)  + ldin(b, lane + 64, f));
    dst[lane + 128] = f2bf((v2 - mu) * rs * ldin(g, lane + 128, f) + ldin(b, lane + 128, f));
}

extern "C" void kernel_launch(void* const* d_in, const int* in_sizes, int n_in,
                              void* d_out, int out_size, void* d_ws, size_t ws_size,
                              hipStream_t stream) {
    const void* x        = d_in[0];
    const void* attnmask = d_in[1];
    const void* ln1_g    = d_in[2];
    const void* ln1_b    = d_in[3];
    const void* qkv_w    = d_in[4];
    const void* qkv_b    = d_in[5];
    const void* rpb      = d_in[6];
    const void* proj_w   = d_in[7];
    const void* proj_b   = d_in[8];
    const void* ln2_g    = d_in[9];
    const void* ln2_b    = d_in[10];
    const void* fc1_w    = d_in[11];
    const void* fc1_b    = d_in[12];
    const void* fc2_w    = d_in[13];
    const void* fc2_b    = d_in[14];
    float* out = (float*)d_out;          // output fp32 (reference dtype)
    char* ws = (char*)d_ws;

    const size_t RSZ = (size_t)TOK * CC * sizeof(bf16);   // 38,535,168
    const size_t WEXT = 442368 * sizeof(bf16)             // 4 transposed weights
                      + (size_t)64 * NHEAD * 64 * 64 * sizeof(bf16)  // comb
                      + 64;                                // flag + pad
    const size_t NEED_BIG = 5 * RSZ + WEXT;                // ~196.7 MB

    const int M = TOK;

    if (ws_size >= NEED_BIG) {
        // ---------------- unchunked path (uses ~197 MB of workspace) ----------------
        // [0,RSZ):      h_win [ln1->qkv]  -> projbuf [proj->resid] -> m1 head
        // [RSZ,4RSZ):   qkv (3*RSZ) [qkv->attn] -> m1 tail (m1 = [0,4RSZ))
        // [4RSZ,5RSZ):  attn_out [attn->proj] -> h2 [resid->fc1]
        // [5RSZ,...):   transposed weights + comb + flag
        bf16* h_win    = (bf16*)(ws);
        bf16* qkvbuf   = (bf16*)(ws + RSZ);
        bf16* attn_out = (bf16*)(ws + 4 * RSZ);
        bf16* projbuf  = (bf16*)(ws);
        bf16* h2       = (bf16*)(ws + 4 * RSZ);
        bf16* m1buf    = (bf16*)(ws);
        bf16* qkvT     = (bf16*)(ws + 5 * RSZ);
        bf16* projT    = qkvT + 192 * 576;
        bf16* fc1T     = projT + 192 * 192;
        bf16* fc2T     = fc1T + 192 * 768;
        bf16* combT    = fc2T + 768 * 192;
        int*  flag     = (int*)(combT + 64 * NHEAD * 64 * 64);

        dtype_probe_kernel<<<1, 64, 0, stream>>>(x, flag);
        transpose_kernel<<<(192 * 576 + 255) / 256, 256, 0, stream>>>(qkv_w, qkvT, 192, 576, flag);
        transpose_kernel<<<(192 * 192 + 255) / 256, 256, 0, stream>>>(proj_w, projT, 192, 192, flag);
        transpose_kernel<<<(192 * 768 + 255) / 256, 256, 0, stream>>>(fc1_w, fc1T, 192, 768, flag);
        transpose_kernel<<<(768 * 192 + 255) / 256, 256, 0, stream>>>(fc2_w, fc2T, 768, 192, flag);
        comb_kernel<<<(64 * NHEAD * 64 * 64) / 256, 256, 0, stream>>>(rpb, attnmask, combT, flag);

        ln1_window_kernel<<<TOK / 4, 256, 0, stream>>>(x, ln1_g, ln1_b, h_win, flag);

        gemm_kernel<0, bf16><<<dim3(576 / 64, M / 128), 256, 0, stream>>>(
            h_win, qkvT, qkv_b, qkvbuf, (const bf16*)nullptr, M, 192, 576, flag);
        attn_mfma_kernel<<<NWIN * NHEAD, 256, 0, stream>>>(qkvbuf, combT, attn_out, 0);

        gemm_kernel<0, bf16><<<dim3(192 / 64, M / 128), 256, 0, stream>>>(
            attn_out, projT, proj_b, projbuf, (const bf16*)nullptr, M, 192, 192, flag);

        resid_ln2_kernel<<<TOK / 4, 256, 0, stream>>>(x, projbuf, ln2_g, ln2_b, out, h2, flag);

        gemm_kernel<1, bf16><<<dim3(768 / 64, M / 128), 256, 0, stream>>>(
            h2, fc1T, fc1_b, m1buf, (const bf16*)nullptr, M, 192, 768, flag);
        gemm_kernel<2, float><<<dim3(192 / 64, M / 128), 256, 0, stream>>>(
            m1buf, fc2T, fc2_b, out, (const float*)out, M, 768, 192, flag);
    } else {
        // ---------------- chunked fallback (~119.6 MB peak, time-disjoint reuse) ----------------
        bf16* h_win    = (bf16*)(ws);
        bf16* m1buf    = (bf16*)(ws);
        bf16* attn_out = (bf16*)(ws + RSZ);
        bf16* h2       = (bf16*)(ws + RSZ);
        bf16* qkvchunk = (bf16*)(ws + 2 * RSZ);
        bf16* projbuf  = (bf16*)(ws + 2 * RSZ);
        bf16* combT    = (bf16*)(ws + 2 * RSZ + 28901376);    // after qkv chunk, within R2
        bf16* qkvT     = (bf16*)(ws + 3 * RSZ);
        bf16* projT    = qkvT + 192 * 576;
        bf16* fc1T     = projT + 192 * 192;
        bf16* fc2T     = fc1T + 192 * 768;
        int*  flag     = (int*)(fc2T + 768 * 192);

        dtype_probe_kernel<<<1, 64, 0, stream>>>(x, flag);
        transpose_kernel<<<(192 * 576 + 255) / 256, 256, 0, stream>>>(qkv_w, qkvT, 192, 576, flag);
        transpose_kernel<<<(192 * 192 + 255) / 256, 256, 0, stream>>>(proj_w, projT, 192, 192, flag);
        transpose_kernel<<<(192 * 768 + 255) / 256, 256, 0, stream>>>(fc1_w, fc1T, 192, 768, flag);
        transpose_kernel<<<(768 * 192 + 255) / 256, 256, 0, stream>>>(fc2_w, fc2T, 768, 192, flag);
        comb_kernel<<<(64 * NHEAD * 64 * 64) / 256, 256, 0, stream>>>(rpb, attnmask, combT, flag);

        ln1_window_kernel<<<TOK / 4, 256, 0, stream>>>(x, ln1_g, ln1_b, h_win, flag);

        const int QCH = 4, QW = NWIN / QCH;          // 512 windows/chunk
        const int QROWS = QW * NT;                   // 25088 rows (divisible by 128)
        for (int c = 0; c < QCH; c++) {
            const bf16* a = h_win + (size_t)c * QROWS * CC;
            gemm_kernel<0, bf16><<<dim3(576 / 64, QROWS / 128), 256, 0, stream>>>(
                a, qkvT, qkv_b, qkvchunk, (const bf16*)nullptr, QROWS, 192, 576, flag);
            attn_mfma_kernel<<<QW * NHEAD, 256, 0, stream>>>(
                qkvchunk, combT, attn_out, c * QW);
        }

        gemm_kernel<0, bf16><<<dim3(192 / 64, M / 128), 256, 0, stream>>>(
            attn_out, projT, proj_b, projbuf, (const bf16*)nullptr, M, 192, 192, flag);

        resid_ln2_kernel<<<TOK / 4, 256, 0, stream>>>(x, projbuf, ln2_g, ln2_b, out, h2, flag);

        const int MCH = 4, MR = TOK / MCH;           // 25088 rows/chunk (divisible by 128)
        for (int c = 0; c < MCH; c++) {
            const bf16* a = h2 + (size_t)c * MR * CC;
            float* oc = out + (size_t)c * MR * CC;
            gemm_kernel<1, bf16><<<dim3(768 / 64, MR / 128), 256, 0, stream>>>(
                a, fc1T, fc1_b, m1buf, (const bf16*)nullptr, MR, 192, 768, flag);
            gemm_kernel<2, float><<<dim3(192 / 64, MR / 128), 256, 0, stream>>>(
                m1buf, fc2T, fc2_b, oc, (const float*)oc, MR, 768, 192, flag);
        }
    }
}

// Round 14
// 508.772 us; speedup vs baseline: 1.1330x; 1.0371x over previous
//
#include <hip/hip_runtime.h>
#include <hip/hip_bf16.h>

typedef __hip_bfloat16 bf16;
typedef __attribute__((ext_vector_type(8))) short short8;
typedef __attribute__((ext_vector_type(4))) float f32x4;
typedef __attribute__((ext_vector_type(4))) unsigned short ushort4_t;

#define TOK 100352      // B * H * W = 32*56*56
#define NWIN 2048       // B * 64 windows
#define CC 192
#define NHEAD 6
#define NT 49           // tokens per window

__device__ __forceinline__ float bf2f(bf16 v) { return __bfloat162float(v); }
__device__ __forceinline__ bf16 f2bf(float v) { return __float2bfloat16(v); }
__device__ __forceinline__ float b2f_bits(unsigned short u) {
    return __uint_as_float(((unsigned)u) << 16);
}

// dtype-agnostic input load: f=1 -> fp32, f=0 -> bf16
__device__ __forceinline__ float ldin(const void* p, size_t i, int f) {
    return f ? ((const float*)p)[i] : bf2f(((const bf16*)p)[i]);
}
// typed store/load for GEMM C/resid
__device__ __forceinline__ void stc(bf16* p, float v) { *p = f2bf(v); }
__device__ __forceinline__ void stc(float* p, float v) { *p = v; }
__device__ __forceinline__ float ldc(const bf16* p) { return bf2f(*p); }
__device__ __forceinline__ float ldc(const float* p) { return *p; }

// fast exact GELU: erf via Abramowitz-Stegun 7.1.26 (|eps| <= 1.5e-7, way below
// bf16 rounding). ~15 VALU inst vs ~50 for libm erff. (verified: absmax unchanged)
__device__ __forceinline__ float gelu_f(float v) {
    float z = v * 0.70710678118654752f;       // v / sqrt(2)
    float az = fabsf(z);
    float t = __builtin_amdgcn_rcpf(1.0f + 0.3275911f * az);
    float p = t * (0.254829592f + t * (-0.284496736f + t * (1.421413741f
            + t * (-1.453152027f + t * 1.061405429f))));
    float e = __expf(-az * az);
    float er = copysignf(1.0f - p * e, z);    // erf(z)
    return 0.5f * v * (1.0f + er);
}

// async global->LDS, 16B per lane; LDS dest is wave-uniform base + lane*16
__device__ __forceinline__ void gl_lds16(const bf16* g, bf16* l) {
    __builtin_amdgcn_global_load_lds(
        (const __attribute__((address_space(1))) unsigned int*)g,
        (__attribute__((address_space(3))) unsigned int*)l, 16, 0, 0);
}

// ---------------- input dtype probe ----------------
__global__ void dtype_probe_kernel(const void* xraw, int* flag) {
    const unsigned short* u = (const unsigned short*)xraw;
    int lane = threadIdx.x & 63;
    int weird = 0;
    for (int i = lane; i < 4096; i += 64) {
        unsigned int bits = ((unsigned int)u[2 * i]) << 16;
        float v = __uint_as_float(bits);
        if (!(fabsf(v) <= 1e10f)) weird++;
    }
    #pragma unroll
    for (int off = 32; off > 0; off >>= 1) weird += __shfl_xor(weird, off, 64);
    if (lane == 0) *flag = (weird > 256) ? 1 : 0;   // 1 = fp32 inputs, 0 = bf16 inputs
}

// ---------------- fused prep: 4 weight transposes + comb table, one dispatch ----------------
// transpose semantics: out[n*K + k] = (bf16)in[k*N + n]
// comb[wi][head][n][m] (64x6x64x64 bf16): rpb[ridx(n,m)][head] + mask[wi][n][m], -1e30 pad.
__global__ __launch_bounds__(256) void prep_kernel(
    const void* __restrict__ qkv_w, const void* __restrict__ proj_w,
    const void* __restrict__ fc1_w, const void* __restrict__ fc2_w,
    const void* __restrict__ rpb, const void* __restrict__ mask,
    bf16* __restrict__ qkvT, bf16* __restrict__ projT,
    bf16* __restrict__ fc1T, bf16* __restrict__ fc2T,
    bf16* __restrict__ comb, const int* __restrict__ flag) {
    int f = *flag;
    int idx = blockIdx.x * 256 + threadIdx.x;
    const int S1 = 192 * 576, S2 = 192 * 192, S3 = 192 * 768, S4 = 768 * 192;
    if (idx < S1) {
        int nn = idx / 192, kk = idx % 192;
        qkvT[idx] = f2bf(ldin(qkv_w, (size_t)kk * 576 + nn, f));
        return;
    }
    idx -= S1;
    if (idx < S2) {
        int nn = idx / 192, kk = idx % 192;
        projT[idx] = f2bf(ldin(proj_w, (size_t)kk * 192 + nn, f));
        return;
    }
    idx -= S2;
    if (idx < S3) {
        int nn = idx / 192, kk = idx % 192;
        fc1T[idx] = f2bf(ldin(fc1_w, (size_t)kk * 768 + nn, f));
        return;
    }
    idx -= S3;
    if (idx < S4) {
        int nn = idx / 768, kk = idx % 768;
        fc2T[idx] = f2bf(ldin(fc2_w, (size_t)kk * 192 + nn, f));
        return;
    }
    idx -= S4;
    {
        int m = idx & 63;
        int n = (idx >> 6) & 63;
        int hw = idx >> 12;                          // wi*NHEAD + head
        int head = hw % NHEAD, wi = hw / NHEAD;
        float v;
        if (n < NT && m < NT) {
            int nr = n / 7, nc = n % 7, mr = m / 7, mc = m % 7;
            int ridx = (nr - mr + 6) * 13 + (nc - mc + 6);
            v = ldin(rpb, (size_t)ridx * NHEAD + head, f)
              + ldin(mask, (size_t)wi * NT * NT + n * NT + m, f);
        } else {
            v = -1e30f;
        }
        comb[idx] = f2bf(v);
    }
}

// ---------------- LN1 + cyclic shift + window partition ----------------
__global__ __launch_bounds__(256) void ln1_window_kernel(
    const void* __restrict__ x, const void* __restrict__ g, const void* __restrict__ b,
    bf16* __restrict__ hwin, const int* __restrict__ flag) {
    int f = *flag;
    int wave = threadIdx.x >> 6, lane = threadIdx.x & 63;
    int t = blockIdx.x * 4 + wave;              // 0..TOK-1, window-layout index
    int bidx = t / (64 * NT);
    int r = t % (64 * NT);
    int wi = r / NT, n = r % NT;
    int wr = wi >> 3, wc = wi & 7;
    int nr = n / 7, nc = n % 7;
    int si = wr * 7 + nr, sj = wc * 7 + nc;     // shifted-image coords
    int oi = si + 3; if (oi >= 56) oi -= 56;    // source (original) coords
    int oj = sj + 3; if (oj >= 56) oj -= 56;
    size_t src = ((size_t)bidx * 3136 + oi * 56 + oj) * CC;
    float v0 = ldin(x, src + lane, f);
    float v1 = ldin(x, src + lane + 64, f);
    float v2 = ldin(x, src + lane + 128, f);
    float s = v0 + v1 + v2;
    float sq = v0 * v0 + v1 * v1 + v2 * v2;
    #pragma unroll
    for (int off = 32; off > 0; off >>= 1) {
        s  += __shfl_xor(s, off, 64);
        sq += __shfl_xor(sq, off, 64);
    }
    float mu = s * (1.f / 192.f);
    float var = fmaxf(sq * (1.f / 192.f) - mu * mu, 0.f);
    float rs = rsqrtf(var + 1e-5f);
    bf16* dst = hwin + (size_t)t * CC;
    dst[lane]       = f2bf((v0 - mu) * rs * ldin(g, lane, f)       + ldin(b, lane, f));
    dst[lane + 64]  = f2bf((v1 - mu) * rs * ldin(g, lane + 64, f)  + ldin(b, lane + 64, f));
    dst[lane + 128] = f2bf((v2 - mu) * rs * ldin(g, lane + 128, f) + ldin(b, lane + 128, f));
}

// ---------------- MFMA GEMM: C[M][Nc] = A[M][K] @ Wt[Nc][K]^T + bias ----
// BM=128, BN=64, BK=32. 4 waves, each owns a 32x64 output sub-tile (8 MFMA / K-step).
// 3-buffer depth-2 pipeline: stage tile t+2 each iter, counted s_waitcnt vmcnt(3)
// + raw s_barrier (never drain to 0 in the loop) -> load latency spans 2 iterations.
// Bank swizzle (round 11, conflicts 5.42M->0): linear gl_lds16 dest + pre-swizzled
// global SOURCE k-offset + matching swizzled read. XCD-aware bijective block swizzle.
// EPI: 0 = none, 1 = fast exact GELU, 2 = add residual (resid may alias C; same-elem RMW)
template <int EPI, typename CT>
__global__ __launch_bounds__(256, 4) void gemm_kernel(
    const bf16* __restrict__ A, const bf16* __restrict__ Wt,
    const void* __restrict__ bias, CT* __restrict__ C,
    const CT* __restrict__ resid, int M, int K, int Nc, const int* __restrict__ flag) {
    int f = *flag;
    __shared__ __align__(16) bf16 sb[3][6144];   // per buffer: A 128x32 @0, B 64x32 @4096
    int tid = threadIdx.x;
    int wave = tid >> 6, lane = tid & 63;
    int quad = lane >> 4, l16 = lane & 15;

    // XCD-aware swizzle (chunked, bijective when nwg % 8 == 0)
    int nwg = gridDim.x * gridDim.y;
    int bid = blockIdx.y * gridDim.x + blockIdx.x;
    int swz = bid;
    if ((nwg & 7) == 0) {
        int cpx = nwg >> 3;
        swz = (bid & 7) * cpx + (bid >> 3);
    }
    int bn = swz % gridDim.x, bm = swz / gridDim.x;

    // bank-conflict swizzle: source k-elem offset (staging) and read quad offset
    int swzk = (((lane & 3) ^ ((lane >> 3) & 3)) * 8);      // per-lane source k offset
    int q2   = (quad ^ ((l16 >> 1) & 3)) * 8;               // per-lane read k offset

    // per-lane global staging pointers (tile t = +t*32 along K), source pre-swizzled
    const bf16* ag[2];
    #pragma unroll
    for (int j = 0; j < 2; j++)
        ag[j] = A + (size_t)(bm * 128 + (wave * 2 + j) * 16 + (lane >> 2)) * K + swzk;
    const bf16* bg = Wt + (size_t)(bn * 64 + wave * 16 + (lane >> 2)) * K + swzk;

    auto STAGE = [&](int t, int buf) {
        gl_lds16(ag[0] + (size_t)t * 32, &sb[buf][(wave * 2 + 0) * 512]);
        gl_lds16(ag[1] + (size_t)t * 32, &sb[buf][(wave * 2 + 1) * 512]);
        gl_lds16(bg    + (size_t)t * 32, &sb[buf][4096 + wave * 512]);
    };

    f32x4 acc[2][4];
    #pragma unroll
    for (int i = 0; i < 2; i++)
        #pragma unroll
        for (int j = 0; j < 4; j++)
            acc[i][j][0] = acc[i][j][1] = acc[i][j][2] = acc[i][j][3] = 0.f;

    const int nt = K >> 5;

    // prologue: tiles 0,1 in flight; wait tile 0 only (3 of 6 loads)
    STAGE(0, 0);
    STAGE(1, 1);
    asm volatile("s_waitcnt vmcnt(3)" ::: "memory");
    __builtin_amdgcn_s_barrier();

    int cur = 0;
    for (int t = 0; t < nt; t++) {
        if (t + 2 < nt) {
            int stg = cur + 2; if (stg >= 3) stg -= 3;
            STAGE(t + 2, stg);                  // overwrites buffer consumed at t-1
        }
        const bf16* sA = &sb[cur][0];
        const bf16* sB = &sb[cur][4096];
        short8 av[2], bv[4];
        #pragma unroll
        for (int tm = 0; tm < 2; tm++)
            av[tm] = *(const short8*)(&sA[(wave * 32 + tm * 16 + l16) * 32 + q2]);
        #pragma unroll
        for (int tn = 0; tn < 4; tn++)
            bv[tn] = *(const short8*)(&sB[(tn * 16 + l16) * 32 + q2]);
        #pragma unroll
        for (int tm = 0; tm < 2; tm++)
            #pragma unroll
            for (int tn = 0; tn < 4; tn++)
                acc[tm][tn] = __builtin_amdgcn_mfma_f32_16x16x32_bf16(av[tm], bv[tn], acc[tm][tn], 0, 0, 0);
        if (t + 1 < nt) {
            // tile t+1 resident (oldest 3 loads done); this wave's ds_reads done
            if (t + 2 < nt)
                asm volatile("s_waitcnt vmcnt(3) lgkmcnt(0)" ::: "memory");
            else
                asm volatile("s_waitcnt vmcnt(0) lgkmcnt(0)" ::: "memory");
            __builtin_amdgcn_s_barrier();
        }
        cur++; if (cur >= 3) cur -= 3;
    }

    #pragma unroll
    for (int tm = 0; tm < 2; tm++)
        #pragma unroll
        for (int tn = 0; tn < 4; tn++) {
            int col = bn * 64 + tn * 16 + l16;
            float bvs = ldin(bias, col, f);
            #pragma unroll
            for (int r = 0; r < 4; r++) {
                int row = bm * 128 + wave * 32 + tm * 16 + quad * 4 + r;
                float v = acc[tm][tn][r] + bvs;
                if (EPI == 1) v = gelu_f(v);
                if (EPI == 2) v += ldc(&resid[(size_t)row * Nc + col]);
                stc(&C[(size_t)row * Nc + col], v);
            }
        }
}

// ---------------- MFMA fused window attention: one block per (window, head) ----------------
// Swapped-operand QK^T (mfma(K,Q)) -> each lane holds 16 S-values of ONE query row.
// Softmax fully in-register. V staged with ONE uint4 load/thread + ds transpose scatter.
// P is WAVE-LOCAL (wave tm writes and reads only rows tm*16..tm*16+15) -> no barrier
// between softmax and PV (same-wave LDS ordering via lgkmcnt). comb loads hoisted
// ahead of the QK^T MFMAs so their global latency overlaps compute. 6 blocks/CU.
__global__ __launch_bounds__(256) void attn_mfma_kernel(
    const bf16* __restrict__ qkv, const bf16* __restrict__ comb,
    bf16* __restrict__ attn_out, int wbase) {
    __shared__ __align__(16) bf16 Qs[64 * 40];
    __shared__ __align__(16) bf16 Ks[64 * 40];
    __shared__ __align__(16) bf16 Vt[32 * 72];
    __shared__ __align__(16) bf16 P[64 * 72];

    int head = blockIdx.x % NHEAD;
    int wl = blockIdx.x / NHEAD;      // window within chunk
    int wg = wbase + wl;              // global window
    int wi = wg & 63;                 // mask index (windows per image = 64)
    int t0 = wl * NT;                 // chunk-relative token base
    int tg = wg * NT;                 // global token base
    int tid = threadIdx.x;
    int wave = tid >> 6, lane = tid & 63;
    int quad = lane >> 4, l16 = lane & 15;

    // stage Q,K (64 rows x 32, zero rows >= 49); V via vector load + transpose scatter
    {
        int row = tid >> 2;
        int dc = (tid & 3) * 8;
        uint4 qv = make_uint4(0, 0, 0, 0), kv = qv, vv = qv;
        if (row < NT) {
            const bf16* base = qkv + (size_t)(t0 + row) * 576 + head * 32 + dc;
            qv = *(const uint4*)(base);
            kv = *(const uint4*)(base + 192);
            vv = *(const uint4*)(base + 384);
        }
        *(uint4*)(&Qs[row * 40 + dc]) = qv;
        *(uint4*)(&Ks[row * 40 + dc]) = kv;
        bf16 tv[8];
        *(uint4*)tv = vv;
        #pragma unroll
        for (int r = 0; r < 8; r++)
            Vt[(dc + r) * 72 + row] = tv[r];    // Vt[d][m], zeros for rows >= NT
    }
    __syncthreads();

    const float scale = 0.17677669529663687f;  // 1/sqrt(32)
    int tm = wave;
    int q = tm * 16 + l16;                      // this lane's query row
    const bf16* crow = comb + (((size_t)wi * NHEAD + head) * 64 + q) * 64;

    // hoist comb loads: global latency overlaps the QK^T MFMAs below
    ushort4_t cb[4];
    #pragma unroll
    for (int tn = 0; tn < 4; tn++)
        cb[tn] = *(const ushort4_t*)(crow + tn * 16 + quad * 4);

    // S row in registers: s[tn][r] = S[q][tn*16 + quad*4 + r]
    float s[4][4];
    short8 bfrag = *(const short8*)(&Qs[q * 40 + quad * 8]);
    f32x4 z; z[0] = z[1] = z[2] = z[3] = 0.f;
    #pragma unroll
    for (int tn = 0; tn < 4; tn++) {
        short8 afrag = *(const short8*)(&Ks[(tn * 16 + l16) * 40 + quad * 8]);
        f32x4 acc = __builtin_amdgcn_mfma_f32_16x16x32_bf16(afrag, bfrag, z, 0, 0, 0);
        s[tn][0] = acc[0] * scale + b2f_bits(cb[tn][0]);
        s[tn][1] = acc[1] * scale + b2f_bits(cb[tn][1]);
        s[tn][2] = acc[2] * scale + b2f_bits(cb[tn][2]);
        s[tn][3] = acc[3] * scale + b2f_bits(cb[tn][3]);
    }

    // in-register softmax over the 64 keys of query q (16 in-lane + quad group)
    float mx = s[0][0];
    #pragma unroll
    for (int tn = 0; tn < 4; tn++)
        #pragma unroll
        for (int r = 0; r < 4; r++) mx = fmaxf(mx, s[tn][r]);
    mx = fmaxf(mx, __shfl_xor(mx, 16, 64));
    mx = fmaxf(mx, __shfl_xor(mx, 32, 64));
    float sm = 0.f;
    #pragma unroll
    for (int tn = 0; tn < 4; tn++)
        #pragma unroll
        for (int r = 0; r < 4; r++) { s[tn][r] = __expf(s[tn][r] - mx); sm += s[tn][r]; }
    sm += __shfl_xor(sm, 16, 64);
    sm += __shfl_xor(sm, 32, 64);
    float inv = 1.0f / sm;

    // write P row segments; wave tm touches ONLY rows tm*16..tm*16+15
    #pragma unroll
    for (int tn = 0; tn < 4; tn++) {
        bf16 pk[4];
        #pragma unroll
        for (int r = 0; r < 4; r++) pk[r] = f2bf(s[tn][r] * inv);
        *(uint2*)(&P[q * 72 + tn * 16 + quad * 4]) = *(const uint2*)pk;
    }
    // no barrier: PV below reads only this wave's P rows (same-wave LDS ordering)

    // O = P @ V   (M=64 rows, N=32 dims, K=64 over keys)
    f32x4 oacc[2];
    oacc[0][0] = oacc[0][1] = oacc[0][2] = oacc[0][3] = 0.f;
    oacc[1] = oacc[0];
    #pragma unroll
    for (int kc = 0; kc < 2; kc++) {
        short8 pa = *(const short8*)(&P[(tm * 16 + l16) * 72 + kc * 32 + quad * 8]);
        #pragma unroll
        for (int tn = 0; tn < 2; tn++) {
            short8 vb = *(const short8*)(&Vt[(tn * 16 + l16) * 72 + kc * 32 + quad * 8]);
            oacc[tn] = __builtin_amdgcn_mfma_f32_16x16x32_bf16(pa, vb, oacc[tn], 0, 0, 0);
        }
    }
    #pragma unroll
    for (int tn = 0; tn < 2; tn++) {
        #pragma unroll
        for (int r = 0; r < 4; r++) {
            int n = tm * 16 + quad * 4 + r;
            int d = tn * 16 + l16;
            if (n < NT)
                attn_out[(size_t)(tg + n) * CC + head * 32 + d] = f2bf(oacc[tn][r]);
        }
    }
}

// ---------------- window-reverse + unshift + residual + LN2 ----------------
// x1 (FP32) goes into d_out (read back by FC2 epilogue, overwritten in place)
__global__ __launch_bounds__(256) void resid_ln2_kernel(
    const void* __restrict__ x, const bf16* __restrict__ proj,
    const void* __restrict__ g, const void* __restrict__ b,
    float* __restrict__ x1, bf16* __restrict__ h2, const int* __restrict__ flag) {
    int f = *flag;
    int wave = threadIdx.x >> 6, lane = threadIdx.x & 63;
    int tok = blockIdx.x * 4 + wave;          // original token order
    int bidx = tok / 3136;
    int r = tok % 3136;
    int i = r / 56, j = r % 56;
    int si = i + 53; if (si >= 56) si -= 56;  // (i - 3) mod 56
    int sj = j + 53; if (sj >= 56) sj -= 56;
    int wi = (si / 7) * 8 + sj / 7;
    int n = (si % 7) * 7 + (sj % 7);
    size_t tw = ((size_t)bidx * 64 + wi) * NT + n;
    const bf16* ps = proj + tw * CC;
    size_t xs = (size_t)tok * CC;
    float v0 = ldin(x, xs + lane, f)       + bf2f(ps[lane]);
    float v1 = ldin(x, xs + lane + 64, f)  + bf2f(ps[lane + 64]);
    float v2 = ldin(x, xs + lane + 128, f) + bf2f(ps[lane + 128]);
    float* xd = x1 + (size_t)tok * CC;
    xd[lane] = v0; xd[lane + 64] = v1; xd[lane + 128] = v2;
    float s = v0 + v1 + v2;
    float sq = v0 * v0 + v1 * v1 + v2 * v2;
    #pragma unroll
    for (int off = 32; off > 0; off >>= 1) {
        s  += __shfl_xor(s, off, 64);
        sq += __shfl_xor(sq, off, 64);
    }
    float mu = s * (1.f / 192.f);
    float var = fmaxf(sq * (1.f / 192.f) - mu * mu, 0.f);
    float rs = rsqrtf(var + 1e-5f);
    bf16* dst = h2 + (size_t)tok * CC;
    dst[lane]       = f2bf((v0 - mu) * rs * ldin(g, lane, f)       + ldin(b, lane, f));
    dst[lane + 64]  = f2bf((v1 - mu) * rs * ldin(g, lane + 64, f)  + ldin(b, lane + 64, f));
    dst[lane + 128] = f2bf((v2 - mu) * rs * ldin(g, lane + 128, f) + ldin(b, lane + 128, f));
}

extern "C" void kernel_launch(void* const* d_in, const int* in_sizes, int n_in,
                              void* d_out, int out_size, void* d_ws, size_t ws_size,
                              hipStream_t stream) {
    const void* x        = d_in[0];
    const void* attnmask = d_in[1];
    const void* ln1_g    = d_in[2];
    const void* ln1_b    = d_in[3];
    const void* qkv_w    = d_in[4];
    const void* qkv_b    = d_in[5];
    const void* rpb      = d_in[6];
    const void* proj_w   = d_in[7];
    const void* proj_b   = d_in[8];
    const void* ln2_g    = d_in[9];
    const void* ln2_b    = d_in[10];
    const void* fc1_w    = d_in[11];
    const void* fc1_b    = d_in[12];
    const void* fc2_w    = d_in[13];
    const void* fc2_b    = d_in[14];
    float* out = (float*)d_out;          // output fp32 (reference dtype)
    char* ws = (char*)d_ws;

    const size_t RSZ = (size_t)TOK * CC * sizeof(bf16);   // 38,535,168
    const size_t WEXT = 442368 * sizeof(bf16)             // 4 transposed weights
                      + (size_t)64 * NHEAD * 64 * 64 * sizeof(bf16)  // comb
                      + 64;                                // flag + pad
    const size_t NEED_BIG = 5 * RSZ + WEXT;                // ~196.7 MB

    const int M = TOK;
    const int PREP_ELEMS = 192 * 576 + 192 * 192 + 192 * 768 + 768 * 192
                         + 64 * NHEAD * 64 * 64;           // 2,015,232 (= 7872 * 256)

    if (ws_size >= NEED_BIG) {
        // ---------------- unchunked path (uses ~197 MB of workspace) ----------------
        // [0,RSZ):      h_win [ln1->qkv]  -> projbuf [proj->resid] -> m1 chunks
        // [RSZ,4RSZ):   qkv (3*RSZ) [qkv->attn] (m1 chunk = 77 MB fits [0,2RSZ))
        // [4RSZ,5RSZ):  attn_out [attn->proj] -> h2 [resid->fc1]
        // [5RSZ,...):   transposed weights + comb + flag
        bf16* h_win    = (bf16*)(ws);
        bf16* qkvbuf   = (bf16*)(ws + RSZ);
        bf16* attn_out = (bf16*)(ws + 4 * RSZ);
        bf16* projbuf  = (bf16*)(ws);
        bf16* h2       = (bf16*)(ws + 4 * RSZ);
        bf16* m1buf    = (bf16*)(ws);
        bf16* qkvT     = (bf16*)(ws + 5 * RSZ);
        bf16* projT    = qkvT + 192 * 576;
        bf16* fc1T     = projT + 192 * 192;
        bf16* fc2T     = fc1T + 192 * 768;
        bf16* combT    = fc2T + 768 * 192;
        int*  flag     = (int*)(combT + 64 * NHEAD * 64 * 64);

        dtype_probe_kernel<<<1, 64, 0, stream>>>(x, flag);
        prep_kernel<<<PREP_ELEMS / 256, 256, 0, stream>>>(
            qkv_w, proj_w, fc1_w, fc2_w, rpb, attnmask,
            qkvT, projT, fc1T, fc2T, combT, flag);

        ln1_window_kernel<<<TOK / 4, 256, 0, stream>>>(x, ln1_g, ln1_b, h_win, flag);

        gemm_kernel<0, bf16><<<dim3(576 / 64, M / 128), 256, 0, stream>>>(
            h_win, qkvT, qkv_b, qkvbuf, (const bf16*)nullptr, M, 192, 576, flag);
        attn_mfma_kernel<<<NWIN * NHEAD, 256, 0, stream>>>(qkvbuf, combT, attn_out, 0);

        gemm_kernel<0, bf16><<<dim3(192 / 64, M / 128), 256, 0, stream>>>(
            attn_out, projT, proj_b, projbuf, (const bf16*)nullptr, M, 192, 192, flag);

        resid_ln2_kernel<<<TOK / 4, 256, 0, stream>>>(x, projbuf, ln2_g, ln2_b, out, h2, flag);

        // MLP chunked MCH=2: each m1 chunk (77 MB) stays L3-resident for its fc2
        const int MCH = 2, MR = TOK / MCH;           // 50176 rows/chunk (divisible by 128)
        for (int c = 0; c < MCH; c++) {
            const bf16* a = h2 + (size_t)c * MR * CC;
            float* oc = out + (size_t)c * MR * CC;
            gemm_kernel<1, bf16><<<dim3(768 / 64, MR / 128), 256, 0, stream>>>(
                a, fc1T, fc1_b, m1buf, (const bf16*)nullptr, MR, 192, 768, flag);
            gemm_kernel<2, float><<<dim3(192 / 64, MR / 128), 256, 0, stream>>>(
                m1buf, fc2T, fc2_b, oc, (const float*)oc, MR, 768, 192, flag);
        }
    } else {
        // ---------------- chunked fallback (~119.6 MB peak, time-disjoint reuse) ----------------
        bf16* h_win    = (bf16*)(ws);
        bf16* m1buf    = (bf16*)(ws);
        bf16* attn_out = (bf16*)(ws + RSZ);
        bf16* h2       = (bf16*)(ws + RSZ);
        bf16* qkvchunk = (bf16*)(ws + 2 * RSZ);
        bf16* projbuf  = (bf16*)(ws + 2 * RSZ);
        bf16* combT    = (bf16*)(ws + 2 * RSZ + 28901376);    // after qkv chunk, within R2
        bf16* qkvT     = (bf16*)(ws + 3 * RSZ);
        bf16* projT    = qkvT + 192 * 576;
        bf16* fc1T     = projT + 192 * 192;
        bf16* fc2T     = fc1T + 192 * 768;
        int*  flag     = (int*)(fc2T + 768 * 192);

        dtype_probe_kernel<<<1, 64, 0, stream>>>(x, flag);
        prep_kernel<<<PREP_ELEMS / 256, 256, 0, stream>>>(
            qkv_w, proj_w, fc1_w, fc2_w, rpb, attnmask,
            qkvT, projT, fc1T, fc2T, combT, flag);

        ln1_window_kernel<<<TOK / 4, 256, 0, stream>>>(x, ln1_g, ln1_b, h_win, flag);

        const int QCH = 4, QW = NWIN / QCH;          // 512 windows/chunk
        const int QROWS = QW * NT;                   // 25088 rows (divisible by 128)
        for (int c = 0; c < QCH; c++) {
            const bf16* a = h_win + (size_t)c * QROWS * CC;
            gemm_kernel<0, bf16><<<dim3(576 / 64, QROWS / 128), 256, 0, stream>>>(
                a, qkvT, qkv_b, qkvchunk, (const bf16*)nullptr, QROWS, 192, 576, flag);
            attn_mfma_kernel<<<QW * NHEAD, 256, 0, stream>>>(
                qkvchunk, combT, attn_out, c * QW);
        }

        gemm_kernel<0, bf16><<<dim3(192 / 64, M / 128), 256, 0, stream>>>(
            attn_out, projT, proj_b, projbuf, (const bf16*)nullptr, M, 192, 192, flag);

        resid_ln2_kernel<<<TOK / 4, 256, 0, stream>>>(x, projbuf, ln2_g, ln2_b, out, h2, flag);

        const int MCH = 4, MR = TOK / MCH;           // 25088 rows/chunk (divisible by 128)
        for (int c = 0; c < MCH; c++) {
            const bf16* a = h2 + (size_t)c * MR * CC;
            float* oc = out + (size_t)c * MR * CC;
            gemm_kernel<1, bf16><<<dim3(768 / 64, MR / 128), 256, 0, stream>>>(
                a, fc1T, fc1_b, m1buf, (const bf16*)nullptr, MR, 192, 768, flag);
            gemm_kernel<2, float><<<dim3(192 / 64, MR / 128), 256, 0, stream>>>(
                m1buf, fc2T, fc2_b, oc, (const float*)oc, MR, 768, 192, flag);
        }
    }
}